// Round 11
// baseline (311.274 us; speedup 1.0000x reference)
//
#include <hip/hip_runtime.h>
#include <math.h>

// Problem constants (B=16, T=2048, D=1024, K=8)
#define BT    32768   // B*T rows
#define DD    1024    // D
#define DV    256     // float4 per row (D/4)
#define KC    8       // clusters
#define NPART 512     // kA grid (round-7 proven config)
#define RPBA  64      // rows per kA block
#define G3    2048    // kC grid
#define RPB3  16      // rows per kC block

// clang native vector type (required by __builtin_nontemporal_store).
typedef float fv4 __attribute__((ext_vector_type(4)));

// ---------------------------------------------------------------------------
// DIAGNOSTIC ROUND. Structure = round 7 (83.3us best). kA repeats its whole
// pass 8x, kC repeats its main pass 3x (runtime rep count + per-rep memory
// clobber so loads re-issue; every rep writes identical values -> output
// bit-identical, deterministic). Purpose: push my dispatches above the
// harness's 75-80us poison-fill dispatches so they appear in rocprof top-5
// WITH counters, splitting the unexplained ~28us between kA and kC.
// ---------------------------------------------------------------------------

__global__ __launch_bounds__(256) void kA_diag(const float* __restrict__ x,
                                               float* __restrict__ part,
                                               int reps) {
    const int tid = threadIdx.x;
    const fv4* xv = (const fv4*)x;
    const long row0 = (long)blockIdx.x * RPBA;

    for (int rep = 0; rep < reps; ++rep) {
        __asm__ __volatile__("" ::: "memory");   // force re-load each rep
        fv4 acc = (fv4)(0.f);
        for (int r = 0; r < RPBA; r += 8) {
            fv4 v[8];
#pragma unroll
            for (int i = 0; i < 8; ++i)
                v[i] = xv[(row0 + r + i) * DV + tid];
#pragma unroll
            for (int i = 0; i < 8; ++i) acc += v[i];
        }
        ((fv4*)part)[(long)blockIdx.x * DV + tid] = acc;
    }
}

__global__ __launch_bounds__(256) void kB_fold(const float* __restrict__ part,
                                               float* __restrict__ colsum) {
    const int tid = threadIdx.x;
    const int b = blockIdx.x;
    __shared__ fv4 red[256];

    fv4 a = ((const fv4*)part)[(long)tid * DV + b] +
            ((const fv4*)part)[(long)(tid + 256) * DV + b];
    red[tid] = a;
    __syncthreads();
#pragma unroll
    for (int s = 128; s > 0; s >>= 1) {
        if (tid < s) red[tid] += red[tid + s];
        __syncthreads();
    }
    if (tid == 0) ((fv4*)colsum)[b] = red[0];
}

__global__ __launch_bounds__(256) void kC_diag(const float* __restrict__ x,
                                               const float* __restrict__ mus,
                                               const float* __restrict__ wmix,
                                               const float* __restrict__ log_tau,
                                               const float* __restrict__ log_blend,
                                               const float* __restrict__ colsum,
                                               float* __restrict__ out,
                                               int reps) {
    const int tid = threadIdx.x;
    const long row0 = (long)blockIdx.x * RPB3;
    const fv4* xv = (const fv4*)x;

    // ---- responsibilities (redundant per block, once) --------------------
    float rk[KC];
    {
        const float inv_bt = 1.0f / (float)BT;
        fv4 s = ((const fv4*)colsum)[tid];
        float m[4] = { s.x * inv_bt, s.y * inv_bt, s.z * inv_bt, s.w * inv_bt };
        float prt[KC];
#pragma unroll
        for (int k = 0; k < KC; ++k) {
            fv4 mu = ((const fv4*)mus)[k * DV + tid];
            float d0 = m[0] - mu.x, d1 = m[1] - mu.y;
            float d2 = m[2] - mu.z, d3 = m[3] - mu.w;
            prt[k] = d0 * d0 + d1 * d1 + d2 * d2 + d3 * d3;
        }
        __shared__ float l2[KC][4];
        const int lane = tid & 63, wv = tid >> 6;
#pragma unroll
        for (int k = 0; k < KC; ++k) {
            float v = prt[k];
#pragma unroll
            for (int off = 32; off > 0; off >>= 1) v += __shfl_down(v, off, 64);
            if (lane == 0) l2[k][wv] = v;
        }
        __syncthreads();
        float logits[KC], mx = -1e30f;
#pragma unroll
        for (int k = 0; k < KC; ++k) {
            float tot = l2[k][0] + l2[k][1] + l2[k][2] + l2[k][3];
            float dist = sqrtf(tot * (1.0f / (float)DD));
            logits[k] = logf(wmix[k]) - dist;
            mx = fmaxf(mx, logits[k]);
        }
        float se = 0.f, e[KC];
#pragma unroll
        for (int k = 0; k < KC; ++k) { e[k] = expf(logits[k] - mx); se += e[k]; }
        float is = 1.f / se;
#pragma unroll
        for (int k = 0; k < KC; ++k) rk[k] = e[k] * is;
    }

    // ---- per-column constants (once) -------------------------------------
    const float LOG2E = 1.44269504f;
    fv4 lt = ((const fv4*)log_tau)[tid];
    fv4 lb = ((const fv4*)log_blend)[tid];
    float tl[4], al[4];
    tl[0] = __builtin_amdgcn_exp2f(lt.x * LOG2E) * LOG2E;
    tl[1] = __builtin_amdgcn_exp2f(lt.y * LOG2E) * LOG2E;
    tl[2] = __builtin_amdgcn_exp2f(lt.z * LOG2E) * LOG2E;
    tl[3] = __builtin_amdgcn_exp2f(lt.w * LOG2E) * LOG2E;
    al[0] = 1.f / (1.f + __builtin_amdgcn_exp2f(-lb.x * LOG2E));
    al[1] = 1.f / (1.f + __builtin_amdgcn_exp2f(-lb.y * LOG2E));
    al[2] = 1.f / (1.f + __builtin_amdgcn_exp2f(-lb.z * LOG2E));
    al[3] = 1.f / (1.f + __builtin_amdgcn_exp2f(-lb.w * LOG2E));

    float mu[KC][4];
#pragma unroll
    for (int k = 0; k < KC; ++k) {
        fv4 m4 = ((const fv4*)mus)[k * DV + tid];
        mu[k][0] = m4.x; mu[k][1] = m4.y; mu[k][2] = m4.z; mu[k][3] = m4.w;
    }

    // ---- main pass, repeated `reps` times (identical output each rep) ----
    fv4* ov = (fv4*)out;
    for (int rep = 0; rep < reps; ++rep) {
        __asm__ __volatile__("" ::: "memory");   // force re-load each rep
        for (int rr = 0; rr < RPB3; rr += 4) {
            fv4 v[4];
#pragma unroll
            for (int i = 0; i < 4; ++i)
                v[i] = xv[(row0 + rr + i) * DV + tid];
#pragma unroll
            for (int i = 0; i < 4; ++i) {
                float xin[4] = { v[i].x, v[i].y, v[i].z, v[i].w };
                float o[4];
#pragma unroll
                for (int e = 0; e < 4; ++e) {
                    float xe = xin[e];
                    float fam = 0.f;
#pragma unroll
                    for (int k = 0; k < KC; ++k)
                        fam += rk[k] * __builtin_amdgcn_exp2f(-tl[e] * fabsf(xe - mu[k][e]));
                    float y = xe * (1.f - al[e] * fam);
                    float z = 0.79788456f * (y + 0.044715f * y * y * y);
                    float e2 = __builtin_amdgcn_exp2f(2.88539008f * z);
                    float th = 1.f - 2.f * __builtin_amdgcn_rcpf(e2 + 1.f);
                    o[e] = 0.5f * y * (1.f + th);
                }
                fv4 res; res.x = o[0]; res.y = o[1]; res.z = o[2]; res.w = o[3];
                __builtin_nontemporal_store(res, &ov[(row0 + rr + i) * DV + tid]);
            }
        }
    }
}

extern "C" void kernel_launch(void* const* d_in, const int* in_sizes, int n_in,
                              void* d_out, int out_size, void* d_ws, size_t ws_size,
                              hipStream_t stream) {
    const float* x         = (const float*)d_in[0];
    const float* mus       = (const float*)d_in[1];
    const float* wmix      = (const float*)d_in[2];
    const float* log_tau   = (const float*)d_in[3];
    const float* log_blend = (const float*)d_in[4];
    float* out = (float*)d_out;

    float* part   = (float*)d_ws;             // NPART*DD floats (2 MB)
    float* colsum = part + (long)NPART * DD;  // DD floats (4 KB)

    kA_diag<<<NPART, 256, 0, stream>>>(x, part, 8);
    kB_fold<<<DV, 256, 0, stream>>>(part, colsum);
    kC_diag<<<G3, 256, 0, stream>>>(x, mus, wmix, log_tau, log_blend,
                                    colsum, out, 3);
}

// Round 12
// 83.880 us; speedup vs baseline: 3.7109x; 3.7109x over previous
//
#include <hip/hip_runtime.h>
#include <math.h>

// Problem constants (B=16, T=2048, D=1024, K=8)
#define BT    32768   // B*T rows
#define DD    1024    // D
#define DV    256     // float4 per row (D/4)
#define KC    8       // clusters
#define NPART 512     // kA grid (round-7 proven: 24.4us/pass @ 5.5 TB/s measured)
#define G3    1024    // kC grid (was 2048; fewer prologues, more rows/block)
#define RPB3  32      // rows per kC block = BT/G3

// clang native vector type (required by __builtin_nontemporal_store).
typedef float fv4 __attribute__((ext_vector_type(4)));

// ---------------------------------------------------------------------------
// kA: partial column sums. EXACTLY round-7's kA (measured 24.4us/pass,
// 5.5 TB/s at ILP-8 — within 15% of HBM floor; do not touch).
// ---------------------------------------------------------------------------
__global__ __launch_bounds__(256) void kA_partial(const float* __restrict__ x,
                                                  float* __restrict__ part,
                                                  int rows_per_blk) {
    const int tid = threadIdx.x;
    const fv4* xv = (const fv4*)x;
    const long row0 = (long)blockIdx.x * rows_per_blk;
    fv4 acc = (fv4)(0.f);

    for (int r = 0; r < rows_per_blk; r += 8) {
        fv4 v[8];
#pragma unroll
        for (int i = 0; i < 8; ++i)
            v[i] = xv[(row0 + r + i) * DV + tid];
#pragma unroll
        for (int i = 0; i < 8; ++i) acc += v[i];
    }

    ((fv4*)part)[(long)blockIdx.x * DV + tid] = acc;
}

// ---------------------------------------------------------------------------
// kB: parallel fold. EXACTLY round-7's kB (~3us).
// ---------------------------------------------------------------------------
__global__ __launch_bounds__(256) void kB_fold(const float* __restrict__ part,
                                               float* __restrict__ colsum) {
    const int tid = threadIdx.x;
    const int b = blockIdx.x;          // fv4-column index, 0..DV-1
    __shared__ fv4 red[256];

    fv4 a = ((const fv4*)part)[(long)tid * DV + b] +
            ((const fv4*)part)[(long)(tid + 256) * DV + b];
    red[tid] = a;
    __syncthreads();
#pragma unroll
    for (int s = 128; s > 0; s >>= 1) {
        if (tid < s) red[tid] += red[tid + s];
        __syncthreads();
    }
    if (tid == 0) ((fv4*)colsum)[b] = red[0];
}

// ---------------------------------------------------------------------------
// kC: responsibilities + famil/GELU. Round-11 lesson applied: ILP-8 loads
// (was 4) and 1024 blocks x 32 rows (was 2048 x 16) — halves the per-block
// prologue count; mu registers shared between the distance prologue and
// famil (8 fv4 loads/thread saved). NT store unchanged (keeps x L3-resident).
// ---------------------------------------------------------------------------
__global__ __launch_bounds__(256) void kC_main(const float* __restrict__ x,
                                               const float* __restrict__ mus,
                                               const float* __restrict__ wmix,
                                               const float* __restrict__ log_tau,
                                               const float* __restrict__ log_blend,
                                               const float* __restrict__ colsum,
                                               float* __restrict__ out) {
    const int tid = threadIdx.x;
    const long row0 = (long)blockIdx.x * RPB3;
    const fv4* xv = (const fv4*)x;

    // ---- mu loaded ONCE, used by both prologue and famil -----------------
    float mu[KC][4];
#pragma unroll
    for (int k = 0; k < KC; ++k) {
        fv4 m4 = ((const fv4*)mus)[k * DV + tid];
        mu[k][0] = m4.x; mu[k][1] = m4.y; mu[k][2] = m4.z; mu[k][3] = m4.w;
    }

    // ---- responsibilities (redundant per block) --------------------------
    float rk[KC];
    {
        const float inv_bt = 1.0f / (float)BT;
        fv4 s = ((const fv4*)colsum)[tid];
        float m[4] = { s.x * inv_bt, s.y * inv_bt, s.z * inv_bt, s.w * inv_bt };
        float prt[KC];
#pragma unroll
        for (int k = 0; k < KC; ++k) {
            float d0 = m[0] - mu[k][0], d1 = m[1] - mu[k][1];
            float d2 = m[2] - mu[k][2], d3 = m[3] - mu[k][3];
            prt[k] = d0 * d0 + d1 * d1 + d2 * d2 + d3 * d3;
        }
        __shared__ float l2[KC][4];
        const int lane = tid & 63, wv = tid >> 6;
#pragma unroll
        for (int k = 0; k < KC; ++k) {
            float v = prt[k];
#pragma unroll
            for (int off = 32; off > 0; off >>= 1) v += __shfl_down(v, off, 64);
            if (lane == 0) l2[k][wv] = v;
        }
        __syncthreads();
        float logits[KC], mx = -1e30f;
#pragma unroll
        for (int k = 0; k < KC; ++k) {
            float tot = l2[k][0] + l2[k][1] + l2[k][2] + l2[k][3];
            float dist = sqrtf(tot * (1.0f / (float)DD));
            logits[k] = logf(wmix[k]) - dist;
            mx = fmaxf(mx, logits[k]);
        }
        float se = 0.f, e[KC];
#pragma unroll
        for (int k = 0; k < KC; ++k) { e[k] = expf(logits[k] - mx); se += e[k]; }
        float is = 1.f / se;
#pragma unroll
        for (int k = 0; k < KC; ++k) rk[k] = e[k] * is;
    }

    // ---- per-column constants --------------------------------------------
    const float LOG2E = 1.44269504f;
    fv4 lt = ((const fv4*)log_tau)[tid];
    fv4 lb = ((const fv4*)log_blend)[tid];
    float tl[4], al[4];
    tl[0] = __builtin_amdgcn_exp2f(lt.x * LOG2E) * LOG2E;
    tl[1] = __builtin_amdgcn_exp2f(lt.y * LOG2E) * LOG2E;
    tl[2] = __builtin_amdgcn_exp2f(lt.z * LOG2E) * LOG2E;
    tl[3] = __builtin_amdgcn_exp2f(lt.w * LOG2E) * LOG2E;
    al[0] = 1.f / (1.f + __builtin_amdgcn_exp2f(-lb.x * LOG2E));
    al[1] = 1.f / (1.f + __builtin_amdgcn_exp2f(-lb.y * LOG2E));
    al[2] = 1.f / (1.f + __builtin_amdgcn_exp2f(-lb.z * LOG2E));
    al[3] = 1.f / (1.f + __builtin_amdgcn_exp2f(-lb.w * LOG2E));

    // ---- famil / GELU main pass (ILP-8) ----------------------------------
    fv4* ov = (fv4*)out;
    for (int rr = 0; rr < RPB3; rr += 8) {
        fv4 v[8];
#pragma unroll
        for (int i = 0; i < 8; ++i)
            v[i] = xv[(row0 + rr + i) * DV + tid];
#pragma unroll
        for (int i = 0; i < 8; ++i) {
            float xin[4] = { v[i].x, v[i].y, v[i].z, v[i].w };
            float o[4];
#pragma unroll
            for (int e = 0; e < 4; ++e) {
                float xe = xin[e];
                float fam = 0.f;
#pragma unroll
                for (int k = 0; k < KC; ++k)
                    fam += rk[k] * __builtin_amdgcn_exp2f(-tl[e] * fabsf(xe - mu[k][e]));
                float y = xe * (1.f - al[e] * fam);
                float z = 0.79788456f * (y + 0.044715f * y * y * y);
                float e2 = __builtin_amdgcn_exp2f(2.88539008f * z);
                float th = 1.f - 2.f * __builtin_amdgcn_rcpf(e2 + 1.f);
                o[e] = 0.5f * y * (1.f + th);
            }
            fv4 res; res.x = o[0]; res.y = o[1]; res.z = o[2]; res.w = o[3];
            __builtin_nontemporal_store(res, &ov[(row0 + rr + i) * DV + tid]);
        }
    }
}

extern "C" void kernel_launch(void* const* d_in, const int* in_sizes, int n_in,
                              void* d_out, int out_size, void* d_ws, size_t ws_size,
                              hipStream_t stream) {
    const float* x         = (const float*)d_in[0];
    const float* mus       = (const float*)d_in[1];
    const float* wmix      = (const float*)d_in[2];
    const float* log_tau   = (const float*)d_in[3];
    const float* log_blend = (const float*)d_in[4];
    float* out = (float*)d_out;

    float* part   = (float*)d_ws;             // NPART*DD floats (2 MB)
    float* colsum = part + (long)NPART * DD;  // DD floats (4 KB)

    kA_partial<<<NPART, 256, 0, stream>>>(x, part, BT / NPART);
    kB_fold<<<DV, 256, 0, stream>>>(part, colsum);
    kC_main<<<G3, 256, 0, stream>>>(x, mus, wmix, log_tau, log_blend,
                                    colsum, out);
}

// Round 13
// 83.430 us; speedup vs baseline: 3.7309x; 1.0054x over previous
//
#include <hip/hip_runtime.h>
#include <hip/hip_cooperative_groups.h>
#include <math.h>

namespace cg = cooperative_groups;

// Problem constants (B=16, T=2048, D=1024, K=8)
#define BT     32768   // B*T rows
#define DD     1024    // D
#define DV     256     // float4 per row (D/4)
#define KC     8       // clusters
// Fused (cooperative) config: 4 blocks/CU x 256 CUs
#define NBLKF  1024
#define RPBF   32      // rows per block = BT/NBLKF
// Fallback (round-7 proven, 83.3us) config
#define NPART  512
#define G3     2048
#define RPB3   16

typedef float fv4 __attribute__((ext_vector_type(4)));

// ===========================================================================
// FUSED cooperative kernel — one dispatch (rounds 7-12 showed ~25us of the
// 83us total is 3-dispatch graph-node overhead; round 5 showed 1 dispatch
// has ~none). Occupancy fix vs round 5: 1024 blocks (16 waves/CU, was 8)
// and ILP-8 loads (round-11 diag: ILP-8 at 6 waves/CU already = 5.5 TB/s).
//   P1: per-block column sums over its 32 rows -> part[1024][1024]
//   P2a: blocks 0..255 fold part -> colsum (4 loads + LDS tree)
//   P2b: every block redundantly: colsum -> x_mean -> dist -> softmax -> rk
//   P3: famil/GELU over the block's 32 rows, ILP-8, NT store.
// ===========================================================================
__global__ __launch_bounds__(256, 4) void fused(
        const float* __restrict__ x,
        const float* __restrict__ mus,
        const float* __restrict__ wmix,
        const float* __restrict__ log_tau,
        const float* __restrict__ log_blend,
        float* __restrict__ out,
        float* __restrict__ part,
        float* __restrict__ colsum) {
    const int tid = threadIdx.x;
    const int bid = blockIdx.x;
    cg::grid_group grid = cg::this_grid();

    const fv4* xv = (const fv4*)x;
    const long row0 = (long)bid * RPBF;

    __shared__ fv4 red[256];
    __shared__ float l2[KC][4];

    // ---- P1: column partial sums, ILP-8 ----------------------------------
    {
        fv4 acc = (fv4)(0.f);
        for (int r = 0; r < RPBF; r += 8) {
            fv4 v[8];
#pragma unroll
            for (int i = 0; i < 8; ++i)
                v[i] = xv[(row0 + r + i) * DV + tid];
#pragma unroll
            for (int i = 0; i < 8; ++i) acc += v[i];
        }
        ((fv4*)part)[(long)bid * DV + tid] = acc;
    }
    grid.sync();

    // ---- P2a: blocks 0..255 fold fv4-column bid over 1024 partial rows ---
    if (bid < DV) {
        fv4 a = (fv4)(0.f);
#pragma unroll
        for (int j = 0; j < NBLKF / 256; ++j)
            a += ((const fv4*)part)[(long)(tid + j * 256) * DV + bid];
        red[tid] = a;
        __syncthreads();
#pragma unroll
        for (int s = 128; s > 0; s >>= 1) {
            if (tid < s) red[tid] += red[tid + s];
            __syncthreads();
        }
        if (tid == 0) ((fv4*)colsum)[bid] = red[0];
    }
    grid.sync();

    // ---- mu loaded once: used by P2b distance AND P3 famil ---------------
    float mu[KC][4];
#pragma unroll
    for (int k = 0; k < KC; ++k) {
        fv4 m4 = ((const fv4*)mus)[k * DV + tid];
        mu[k][0] = m4.x; mu[k][1] = m4.y; mu[k][2] = m4.z; mu[k][3] = m4.w;
    }

    // ---- P2b: responsibilities (redundant per block) ----------------------
    float rk[KC];
    {
        const float inv_bt = 1.0f / (float)BT;
        fv4 s = ((const fv4*)colsum)[tid];
        float m[4] = { s.x * inv_bt, s.y * inv_bt, s.z * inv_bt, s.w * inv_bt };
        float prt[KC];
#pragma unroll
        for (int k = 0; k < KC; ++k) {
            float d0 = m[0] - mu[k][0], d1 = m[1] - mu[k][1];
            float d2 = m[2] - mu[k][2], d3 = m[3] - mu[k][3];
            prt[k] = d0 * d0 + d1 * d1 + d2 * d2 + d3 * d3;
        }
        const int lane = tid & 63, wv = tid >> 6;
#pragma unroll
        for (int k = 0; k < KC; ++k) {
            float v = prt[k];
#pragma unroll
            for (int off = 32; off > 0; off >>= 1) v += __shfl_down(v, off, 64);
            if (lane == 0) l2[k][wv] = v;
        }
        __syncthreads();
        float logits[KC], mx = -1e30f;
#pragma unroll
        for (int k = 0; k < KC; ++k) {
            float tot = l2[k][0] + l2[k][1] + l2[k][2] + l2[k][3];
            float dist = sqrtf(tot * (1.0f / (float)DD));
            logits[k] = logf(wmix[k]) - dist;
            mx = fmaxf(mx, logits[k]);
        }
        float se = 0.f, e[KC];
#pragma unroll
        for (int k = 0; k < KC; ++k) { e[k] = expf(logits[k] - mx); se += e[k]; }
        float is = 1.f / se;
#pragma unroll
        for (int k = 0; k < KC; ++k) rk[k] = e[k] * is;
    }

    // ---- P3: famil/GELU, ILP-8, NT store ----------------------------------
    {
        const float LOG2E = 1.44269504f;
        fv4 lt = ((const fv4*)log_tau)[tid];
        fv4 lb = ((const fv4*)log_blend)[tid];
        float tl[4], al[4];
        tl[0] = __builtin_amdgcn_exp2f(lt.x * LOG2E) * LOG2E;
        tl[1] = __builtin_amdgcn_exp2f(lt.y * LOG2E) * LOG2E;
        tl[2] = __builtin_amdgcn_exp2f(lt.z * LOG2E) * LOG2E;
        tl[3] = __builtin_amdgcn_exp2f(lt.w * LOG2E) * LOG2E;
        al[0] = 1.f / (1.f + __builtin_amdgcn_exp2f(-lb.x * LOG2E));
        al[1] = 1.f / (1.f + __builtin_amdgcn_exp2f(-lb.y * LOG2E));
        al[2] = 1.f / (1.f + __builtin_amdgcn_exp2f(-lb.z * LOG2E));
        al[3] = 1.f / (1.f + __builtin_amdgcn_exp2f(-lb.w * LOG2E));

        fv4* ov = (fv4*)out;
        for (int rr = 0; rr < RPBF; rr += 8) {
            fv4 v[8];
#pragma unroll
            for (int i = 0; i < 8; ++i)
                v[i] = xv[(row0 + rr + i) * DV + tid];
#pragma unroll
            for (int i = 0; i < 8; ++i) {
                float xin[4] = { v[i].x, v[i].y, v[i].z, v[i].w };
                float o[4];
#pragma unroll
                for (int e = 0; e < 4; ++e) {
                    float xe = xin[e];
                    float fam = 0.f;
#pragma unroll
                    for (int k = 0; k < KC; ++k)
                        fam += rk[k] * __builtin_amdgcn_exp2f(-tl[e] * fabsf(xe - mu[k][e]));
                    float y = xe * (1.f - al[e] * fam);
                    float z = 0.79788456f * (y + 0.044715f * y * y * y);
                    float e2 = __builtin_amdgcn_exp2f(2.88539008f * z);
                    float th = 1.f - 2.f * __builtin_amdgcn_rcpf(e2 + 1.f);
                    o[e] = 0.5f * y * (1.f + th);
                }
                fv4 res; res.x = o[0]; res.y = o[1]; res.z = o[2]; res.w = o[3];
                __builtin_nontemporal_store(res, &ov[(row0 + rr + i) * DV + tid]);
            }
        }
    }
}

// ===========================================================================
// FALLBACK path — byte-identical to round 7's proven 83.3us structure.
// Used only if the occupancy query says <4 co-resident blocks/CU.
// ===========================================================================
__global__ __launch_bounds__(256) void kA_partial(const float* __restrict__ x,
                                                  float* __restrict__ part,
                                                  int rows_per_blk) {
    const int tid = threadIdx.x;
    const fv4* xv = (const fv4*)x;
    const long row0 = (long)blockIdx.x * rows_per_blk;
    fv4 acc = (fv4)(0.f);
    for (int r = 0; r < rows_per_blk; r += 8) {
        fv4 v[8];
#pragma unroll
        for (int i = 0; i < 8; ++i)
            v[i] = xv[(row0 + r + i) * DV + tid];
#pragma unroll
        for (int i = 0; i < 8; ++i) acc += v[i];
    }
    ((fv4*)part)[(long)blockIdx.x * DV + tid] = acc;
}

__global__ __launch_bounds__(256) void kB_fold(const float* __restrict__ part,
                                               float* __restrict__ colsum) {
    const int tid = threadIdx.x;
    const int b = blockIdx.x;
    __shared__ fv4 red[256];
    fv4 a = ((const fv4*)part)[(long)tid * DV + b] +
            ((const fv4*)part)[(long)(tid + 256) * DV + b];
    red[tid] = a;
    __syncthreads();
#pragma unroll
    for (int s = 128; s > 0; s >>= 1) {
        if (tid < s) red[tid] += red[tid + s];
        __syncthreads();
    }
    if (tid == 0) ((fv4*)colsum)[b] = red[0];
}

__global__ __launch_bounds__(256) void kC_main(const float* __restrict__ x,
                                               const float* __restrict__ mus,
                                               const float* __restrict__ wmix,
                                               const float* __restrict__ log_tau,
                                               const float* __restrict__ log_blend,
                                               const float* __restrict__ colsum,
                                               float* __restrict__ out) {
    const int tid = threadIdx.x;
    const long row0 = (long)blockIdx.x * RPB3;
    const fv4* xv = (const fv4*)x;

    float rk[KC];
    {
        const float inv_bt = 1.0f / (float)BT;
        fv4 s = ((const fv4*)colsum)[tid];
        float m[4] = { s.x * inv_bt, s.y * inv_bt, s.z * inv_bt, s.w * inv_bt };
        float prt[KC];
#pragma unroll
        for (int k = 0; k < KC; ++k) {
            fv4 mu = ((const fv4*)mus)[k * DV + tid];
            float d0 = m[0] - mu.x, d1 = m[1] - mu.y;
            float d2 = m[2] - mu.z, d3 = m[3] - mu.w;
            prt[k] = d0 * d0 + d1 * d1 + d2 * d2 + d3 * d3;
        }
        __shared__ float l2[KC][4];
        const int lane = tid & 63, wv = tid >> 6;
#pragma unroll
        for (int k = 0; k < KC; ++k) {
            float v = prt[k];
#pragma unroll
            for (int off = 32; off > 0; off >>= 1) v += __shfl_down(v, off, 64);
            if (lane == 0) l2[k][wv] = v;
        }
        __syncthreads();
        float logits[KC], mx = -1e30f;
#pragma unroll
        for (int k = 0; k < KC; ++k) {
            float tot = l2[k][0] + l2[k][1] + l2[k][2] + l2[k][3];
            float dist = sqrtf(tot * (1.0f / (float)DD));
            logits[k] = logf(wmix[k]) - dist;
            mx = fmaxf(mx, logits[k]);
        }
        float se = 0.f, e[KC];
#pragma unroll
        for (int k = 0; k < KC; ++k) { e[k] = expf(logits[k] - mx); se += e[k]; }
        float is = 1.f / se;
#pragma unroll
        for (int k = 0; k < KC; ++k) rk[k] = e[k] * is;
    }

    const float LOG2E = 1.44269504f;
    fv4 lt = ((const fv4*)log_tau)[tid];
    fv4 lb = ((const fv4*)log_blend)[tid];
    float tl[4], al[4];
    tl[0] = __builtin_amdgcn_exp2f(lt.x * LOG2E) * LOG2E;
    tl[1] = __builtin_amdgcn_exp2f(lt.y * LOG2E) * LOG2E;
    tl[2] = __builtin_amdgcn_exp2f(lt.z * LOG2E) * LOG2E;
    tl[3] = __builtin_amdgcn_exp2f(lt.w * LOG2E) * LOG2E;
    al[0] = 1.f / (1.f + __builtin_amdgcn_exp2f(-lb.x * LOG2E));
    al[1] = 1.f / (1.f + __builtin_amdgcn_exp2f(-lb.y * LOG2E));
    al[2] = 1.f / (1.f + __builtin_amdgcn_exp2f(-lb.z * LOG2E));
    al[3] = 1.f / (1.f + __builtin_amdgcn_exp2f(-lb.w * LOG2E));

    float mu[KC][4];
#pragma unroll
    for (int k = 0; k < KC; ++k) {
        fv4 m4 = ((const fv4*)mus)[k * DV + tid];
        mu[k][0] = m4.x; mu[k][1] = m4.y; mu[k][2] = m4.z; mu[k][3] = m4.w;
    }

    fv4* ov = (fv4*)out;
    for (int rr = 0; rr < RPB3; rr += 4) {
        fv4 v[4];
#pragma unroll
        for (int i = 0; i < 4; ++i)
            v[i] = xv[(row0 + rr + i) * DV + tid];
#pragma unroll
        for (int i = 0; i < 4; ++i) {
            float xin[4] = { v[i].x, v[i].y, v[i].z, v[i].w };
            float o[4];
#pragma unroll
            for (int e = 0; e < 4; ++e) {
                float xe = xin[e];
                float fam = 0.f;
#pragma unroll
                for (int k = 0; k < KC; ++k)
                    fam += rk[k] * __builtin_amdgcn_exp2f(-tl[e] * fabsf(xe - mu[k][e]));
                float y = xe * (1.f - al[e] * fam);
                float z = 0.79788456f * (y + 0.044715f * y * y * y);
                float e2 = __builtin_amdgcn_exp2f(2.88539008f * z);
                float th = 1.f - 2.f * __builtin_amdgcn_rcpf(e2 + 1.f);
                o[e] = 0.5f * y * (1.f + th);
            }
            fv4 res; res.x = o[0]; res.y = o[1]; res.z = o[2]; res.w = o[3];
            __builtin_nontemporal_store(res, &ov[(row0 + rr + i) * DV + tid]);
        }
    }
}

extern "C" void kernel_launch(void* const* d_in, const int* in_sizes, int n_in,
                              void* d_out, int out_size, void* d_ws, size_t ws_size,
                              hipStream_t stream) {
    const float* x         = (const float*)d_in[0];
    const float* mus       = (const float*)d_in[1];
    const float* wmix      = (const float*)d_in[2];
    const float* log_tau   = (const float*)d_in[3];
    const float* log_blend = (const float*)d_in[4];
    float* out = (float*)d_out;

    // Capacity check (host-side query: capture-safe, deterministic).
    int blocksPerCU = 0;
    hipError_t qerr = hipOccupancyMaxActiveBlocksPerMultiprocessor(
        &blocksPerCU, (const void*)fused, 256, 0);
    const bool coop_ok = (qerr == hipSuccess) && (blocksPerCU * 256 >= NBLKF);

    if (coop_ok) {
        float* part   = (float*)d_ws;              // NBLKF*DD floats (4 MB)
        float* colsum = part + (long)NBLKF * DD;   // DD floats (4 KB)
        void* args[] = { (void*)&x, (void*)&mus, (void*)&wmix, (void*)&log_tau,
                         (void*)&log_blend, (void*)&out, (void*)&part,
                         (void*)&colsum };
        (void)hipLaunchCooperativeKernel((const void*)fused, dim3(NBLKF),
                                         dim3(256), args, 0, stream);
    } else {
        float* part   = (float*)d_ws;              // NPART*DD floats (2 MB)
        float* colsum = part + (long)NPART * DD;   // DD floats (4 KB)
        kA_partial<<<NPART, 256, 0, stream>>>(x, part, BT / NPART);
        kB_fold<<<DV, 256, 0, stream>>>(part, colsum);
        kC_main<<<G3, 256, 0, stream>>>(x, mus, wmix, log_tau, log_blend,
                                        colsum, out);
    }
}